// Round 17
// baseline (336.861 us; speedup 1.0000x reference)
//
#include <hip/hip_runtime.h>
#include <stdint.h>

// Problem constants
#define NDM   1024   // D_MODEL
#define NDS   16     // D_STATE
#define NDC   4      // D_CONV
#define NDI   2048   // D_INNER
#define NB    2      // BATCH
#define NL    2048   // SEQ
#define MROWS (NB*NL)   // 4096
#define CCH   32     // scan chunks
#define CLEN  64     // NL / CCH

typedef __bf16 bf16x8 __attribute__((ext_vector_type(8)));
typedef float  f32x4  __attribute__((ext_vector_type(4)));
typedef short  short8 __attribute__((ext_vector_type(8)));

__device__ __forceinline__ short f2bf(float f) {
  union { float f; unsigned u; } x; x.f = f;
  unsigned r = (x.u + 0x7FFFu + ((x.u >> 16) & 1u)) >> 16;
  return (short)r;
}
__device__ __forceinline__ float bf2f(short s) {
  union { unsigned u; float f; } x; x.u = ((unsigned)(unsigned short)s) << 16;
  return x.f;
}

// Fragment-order Global layout (FG): 16-row groups; chunk (k8, r) of 8 shorts
// at k8*128 + (r&15)*8. A 16x32 MFMA fragment = CONTIGUOUS 1KB in lane order.
__device__ __forceinline__ size_t fgoff(int row, int k8, int K) {
  return (size_t)(row >> 4) * K * 16 + (size_t)k8 * 128 + (row & 15) * 8;
}

// ---------------------------------------------------------------------------
// x (f32, MROWS x 1024 row-major) -> FG bf16 via LDS slab
__global__ __launch_bounds__(256) void cvt_fg_kernel(
    const float* __restrict__ in, short* __restrict__ out) {
  __shared__ short slab[16][1032];
  const int tid = threadIdx.x;
  const int g = blockIdx.x;
  const float* p = in + (size_t)g * 16 * 1024;
  #pragma unroll
  for (int u = 0; u < 8; ++u) {
    int unit = u * 256 + tid;
    int rr = unit >> 7, cc = unit & 127;
    const float* rp = p + (size_t)rr * 1024 + cc * 8;
    #pragma unroll
    for (int e = 0; e < 8; ++e) slab[rr][cc * 8 + e] = f2bf(rp[e]);
  }
  __syncthreads();
  short* op = out + (size_t)g * 16384;
  #pragma unroll
  for (int u = 0; u < 8; ++u) {
    int u2 = u * 256 + tid;
    int rr = u2 & 15, k8 = u2 >> 4;
    *(short8*)&op[k8 * 128 + rr * 8] = *(short8*)&slab[rr][k8 * 8];
  }
}

// ---------------------------------------------------------------------------
// W (K x N f32) -> FG bf16 of W^T (N rows, K cols). 32n x 64k tiles.
__global__ __launch_bounds__(256) void transpose_fg_kernel(
    const float* __restrict__ in, short* __restrict__ out, int K, int N) {
  __shared__ float t[64][33];
  const int tx = threadIdx.x, ty = threadIdx.y;   // 32, 8
  const int n0 = blockIdx.x * 32, k0 = blockIdx.y * 64;
  #pragma unroll
  for (int i = 0; i < 64; i += 8)
    t[ty + i][tx] = in[(size_t)(k0 + ty + i) * N + n0 + tx];
  __syncthreads();
  const int n = n0 + tx, k8 = (k0 >> 3) + ty;
  short8 v;
  #pragma unroll
  for (int e = 0; e < 8; ++e) v[e] = f2bf(t[ty * 8 + e][tx]);
  *(short8*)&out[fgoff(n, k8, K)] = v;
}

// ---------------------------------------------------------------------------
// W_x cols 16..31 -> FG rows 2048..2063 of Wcat (group 128). K=2048.
__global__ __launch_bounds__(256) void wx_fg_kernel(
    const float* __restrict__ Wx, short* __restrict__ Wcat) {
  int t = blockIdx.x * 256 + threadIdx.x;     // 4096 = 256 k8 x 16 n
  int k8 = t >> 4, n = t & 15;
  short8 v;
  #pragma unroll
  for (int e = 0; e < 8; ++e)
    v[e] = f2bf(Wx[(size_t)(k8 * 8 + e) * (2 * NDS) + NDS + n]);
  *(short8*)&Wcat[(size_t)128 * 2048 * 16 + (size_t)k8 * 128 + n * 8] = v;
}

// ---------------------------------------------------------------------------
// Register-direct FG bf16 TN GEMM, 128xBN tile (barrier-free; R13 structure).
// BN=64 doubles resident blocks (latency hiding) at the cost of 2x A-side
// L2 traffic — we are ~6x below the L2 ceiling, so TLP wins (R16 theory).
// EPI=0: f32 C + bias (gemm-out)
// EPI=1: delta = softplus(v+bias) -> bf16 FG via LDS ctile (coalesced);
//        cols 2048..2063 -> Bm f32 + bx (fused Bmat); cols >=2064 pad.
// EPI=2: bf16 row-major C via LDS ctile (xz output)
template<int BN, int EPI>
__global__ __launch_bounds__(256, 2) void gemm_fg_kernel(
    const short* __restrict__ A, const short* __restrict__ Bt,
    const float* __restrict__ bias, float* __restrict__ C,
    short* __restrict__ Cb, float* __restrict__ Bm,
    const float* __restrict__ bx, int M, int N, int K)
{
  const int tid  = threadIdx.x;
  const int lane = tid & 63;
  const int w    = tid >> 6;      // wave 0..3
  const int wM   = w >> 1;
  const int wN   = w & 1;
  const int g    = lane >> 4;
  const int r    = lane & 15;

  constexpr int FN  = BN / 32;    // N fragments per wave (4 or 2)
  constexpr int CTS = BN + 8;     // ctile stride (bank spread)
  __shared__ short ctile_s[(EPI == 0) ? 2 : 128 * CTS];

  // XCD-aware swizzle (all grids have nwg % 8 == 0)
  const int nx  = gridDim.x;
  const int nwg = nx * gridDim.y;
  const int bid = blockIdx.y * nx + blockIdx.x;
  const int swz = (bid & 7) * (nwg >> 3) + (bid >> 3);
  const int bm  = (swz / nx) * 128;
  const int bn  = (swz % nx) * BN;

  const short* pA[4];
  const short* pB[FN];
  #pragma unroll
  for (int m = 0; m < 4; ++m)
    pA[m] = A + (size_t)((bm >> 4) + wM * 4 + m) * K * 16 + lane * 8;
  #pragma unroll
  for (int n = 0; n < FN; ++n)
    pB[n] = Bt + (size_t)((bn >> 4) + wN * FN + n) * K * 16 + lane * 8;

  f32x4 acc[4][FN];
  #pragma unroll
  for (int m = 0; m < 4; ++m)
    #pragma unroll
    for (int n = 0; n < FN; ++n)
      acc[m][n] = (f32x4){0.f, 0.f, 0.f, 0.f};

  bf16x8 a0[4], b0[FN], a1[4], b1[FN];
  #pragma unroll
  for (int m = 0; m < 4; ++m) a0[m] = *(const bf16x8*)(pA[m]);
  #pragma unroll
  for (int n = 0; n < FN; ++n) b0[n] = *(const bf16x8*)(pB[n]);

  for (int kb = 0; kb < K; kb += 64) {
    if (kb + 32 < K) {
      #pragma unroll
      for (int m = 0; m < 4; ++m)
        a1[m] = *(const bf16x8*)(pA[m] + (size_t)(kb + 32) * 16);
      #pragma unroll
      for (int n = 0; n < FN; ++n)
        b1[n] = *(const bf16x8*)(pB[n] + (size_t)(kb + 32) * 16);
    }
    #pragma unroll
    for (int m = 0; m < 4; ++m)
      #pragma unroll
      for (int n = 0; n < FN; ++n)
        acc[m][n] = __builtin_amdgcn_mfma_f32_16x16x32_bf16(
            a0[m], b0[n], acc[m][n], 0, 0, 0);

    if (kb + 64 < K) {
      #pragma unroll
      for (int m = 0; m < 4; ++m)
        a0[m] = *(const bf16x8*)(pA[m] + (size_t)(kb + 64) * 16);
      #pragma unroll
      for (int n = 0; n < FN; ++n)
        b0[n] = *(const bf16x8*)(pB[n] + (size_t)(kb + 64) * 16);
    }
    #pragma unroll
    for (int m = 0; m < 4; ++m)
      #pragma unroll
      for (int n = 0; n < FN; ++n)
        acc[m][n] = __builtin_amdgcn_mfma_f32_16x16x32_bf16(
            a1[m], b1[n], acc[m][n], 0, 0, 0);
  }

  // D layout (verified m89/m91): col = lane&15, row = (lane>>4)*4 + e
  if constexpr (EPI == 2) {
    // bf16 row-major epilogue via LDS tile (coalesced row segments)
    short (*ctile)[CTS] = (short(*)[CTS])ctile_s;
    #pragma unroll
    for (int m = 0; m < 4; ++m) {
      const int rl0 = wM * 64 + m * 16 + g * 4;
      #pragma unroll
      for (int n = 0; n < FN; ++n) {
        const int cl = wN * (BN / 2) + n * 16 + r;
        const float bv = bias[bn + cl];
        #pragma unroll
        for (int e = 0; e < 4; ++e)
          ctile[rl0 + e][cl] = f2bf(acc[m][n][e] + bv);
      }
    }
    __syncthreads();
    #pragma unroll
    for (int it = 0; it < (128 * BN / 8) / 256; ++it) {
      int id = it * 256 + tid;
      int rowL = id / (BN / 8), c8 = id % (BN / 8);
      *(short8*)&Cb[(size_t)(bm + rowL) * N + bn + c8 * 8] =
          *(short8*)&ctile[rowL][c8 * 8];
    }
  } else if constexpr (EPI == 1) {
    // delta -> bf16 FG via ctile; Bm side-channel for cols 2048..2063
    short (*ctile)[CTS] = (short(*)[CTS])ctile_s;
    #pragma unroll
    for (int m = 0; m < 4; ++m) {
      const int rl0 = wM * 64 + m * 16 + g * 4;
      const int row0 = bm + rl0;
      #pragma unroll
      for (int n = 0; n < FN; ++n) {
        const int colbase = bn + wN * (BN / 2) + n * 16;
        if (colbase < 2048) {
          const int cl = wN * (BN / 2) + n * 16 + r;
          const float bv = bias[colbase + r];
          #pragma unroll
          for (int e = 0; e < 4; ++e) {
            float v = acc[m][n][e] + bv;
            v = (v > 15.f) ? v : log1pf(__expf(v));
            ctile[rl0 + e][cl] = f2bf(v);
          }
        } else if (colbase == 2048) {
          const float bv = bx[NDS + r];
          #pragma unroll
          for (int e = 0; e < 4; ++e)
            Bm[(size_t)(row0 + e) * NDS + r] = acc[m][n][e] + bv;
        }
      }
    }
    __syncthreads();
    if (bn < 2048) {
      // drain 128xBN ctile into FG (rr-minor -> contiguous 16B chunks)
      constexpr int CH = 2 * BN;          // units per 16-row group
      #pragma unroll
      for (int it = 0; it < (8 * CH) / 256; ++it) {
        int unit = it * 256 + tid;
        int grp = unit / CH, wi = unit % CH;
        int k8l = wi >> 4, rr = wi & 15;
        *(short8*)&Cb[(size_t)((bm >> 4) + grp) * (NDI * 16) +
                      (size_t)((bn >> 3) + k8l) * 128 + rr * 8] =
            *(short8*)&ctile[grp * 16 + rr][k8l * 8];
      }
    }
  } else {
    #pragma unroll
    for (int m = 0; m < 4; ++m) {
      const int row0 = bm + wM * 64 + m * 16 + g * 4;
      #pragma unroll
      for (int n = 0; n < FN; ++n) {
        const int col = bn + wN * (BN / 2) + n * 16 + r;
        const float bv = bias[col];
        #pragma unroll
        for (int e = 0; e < 4; ++e)
          C[(size_t)(row0 + e) * N + col] = acc[m][n][e] + bv;
      }
    }
  }
}

// ---------------------------------------------------------------------------
// depthwise causal conv (width 4) + bias + SiLU; reads bf16 xz;
// writes ONLY xhbf (FG bf16) via slab.
__global__ __launch_bounds__(256) void conv_silu_kernel(
    const short* __restrict__ xz, const float* __restrict__ cw,
    const float* __restrict__ cb, short* __restrict__ xhbf) {
  __shared__ short slab[16][528];
  const int tid = threadIdx.x;
  const int c0 = blockIdx.x * 512;
  const int r0 = blockIdx.y * 16;
  const int b  = r0 >> 11;
  const int t0 = r0 & (NL - 1);
  const short* zbase = xz + ((size_t)b * NL) * (2 * NDI);

  #pragma unroll
  for (int u = 0; u < 4; ++u) {
    int unit = u * 256 + tid;
    int rr = unit >> 6, cc = unit & 63;
    int t = t0 + rr, c = c0 + cc * 8;
    float acc[8];
    #pragma unroll
    for (int e = 0; e < 8; ++e) acc[e] = cb[c + e];
    #pragma unroll
    for (int k = 0; k < NDC; ++k) {
      int tt = t - (NDC - 1) + k;
      if (tt >= 0) {
        short8 rv = *(const short8*)(zbase + (size_t)tt * (2 * NDI) + c);
        #pragma unroll
        for (int e = 0; e < 8; ++e)
          acc[e] += cw[(c + e) * NDC + k] * bf2f(rv[e]);
      }
    }
    #pragma unroll
    for (int e = 0; e < 8; ++e) {
      float s = acc[e] / (1.f + __expf(-acc[e]));
      slab[rr][cc * 8 + e] = f2bf(s);
    }
  }
  __syncthreads();
  short* op = xhbf + (size_t)(r0 >> 4) * NDI * 16 + (size_t)(c0 >> 3) * 128;
  #pragma unroll
  for (int u = 0; u < 4; ++u) {
    int u2 = u * 256 + tid;
    int rr = u2 & 15, q = u2 >> 4;
    *(short8*)&op[q * 128 + rr * 8] = *(short8*)&slab[rr][q * 8];
  }
}

// ---------------------------------------------------------------------------
// scan scratch layout: [b][k][c][s]
__device__ __forceinline__ size_t scoff(int b, int k, int c) {
  return (((size_t)b * CCH + k) * NDI + c) * NDS;
}

// phase 1: thread = (b, c, chunk); 16 states in registers; u,d from FG bf16.
__global__ __launch_bounds__(256) void scan_p1_kernel(
    const short* __restrict__ dbf, const float* __restrict__ Bm,
    const short* __restrict__ xhbf, const float* __restrict__ A_log,
    float* __restrict__ Pbuf, float* __restrict__ Hend) {
  const int i = blockIdx.x * 256 + threadIdx.x;
  const int c = i & (NDI - 1);
  const int k = (i >> 11) & (CCH - 1);
  const int b = i >> 16;
  const int t0 = k * CLEN;

  float Av[NDS];
  #pragma unroll
  for (int s = 0; s < NDS; ++s) Av[s] = -__expf(A_log[c * NDS + s]);

  const size_t fgb = (size_t)((b * NL + t0) >> 4) * (NDI * 16) +
                     (size_t)(c >> 3) * 128 + (c & 7);
  const short* up = xhbf + fgb;
  const short* dp = dbf + fgb;
  const f32x4* Bp = (const f32x4*)(Bm + ((size_t)(b * NL + t0)) * NDS);

  float h[NDS], P[NDS];
  #pragma unroll
  for (int s = 0; s < NDS; ++s) { h[s] = 0.f; P[s] = 1.f; }

  #pragma unroll 4
  for (int j = 0; j < CLEN; ++j) {
    const size_t o = (size_t)(j >> 4) * (NDI * 16) + (j & 15) * 8;
    const float d = bf2f(dp[o]);
    const float u = bf2f(up[o]);
    f32x4 B0 = Bp[j * 4 + 0], B1 = Bp[j * 4 + 1];
    f32x4 B2 = Bp[j * 4 + 2], B3 = Bp[j * 4 + 3];
    const float du = d * u;
    float Bv[NDS];
    #pragma unroll
    for (int e = 0; e < 4; ++e) {
      Bv[e] = B0[e]; Bv[4 + e] = B1[e]; Bv[8 + e] = B2[e]; Bv[12 + e] = B3[e];
    }
    #pragma unroll
    for (int s = 0; s < NDS; ++s) {
      float dA = __expf(d * Av[s]);
      h[s] = dA * h[s] + du * Bv[s];
      P[s] *= dA;
    }
  }

  const size_t base = scoff(b, k, c);
  #pragma unroll
  for (int q = 0; q < 4; ++q) {
    *(f32x4*)&Pbuf[base + q * 4] = (f32x4){P[q*4], P[q*4+1], P[q*4+2], P[q*4+3]};
    *(f32x4*)&Hend[base + q * 4] = (f32x4){h[q*4], h[q*4+1], h[q*4+2], h[q*4+3]};
  }
}

// ---------------------------------------------------------------------------
// phase 2: thread = (b, c, s); serial combine across the chunks.
__global__ __launch_bounds__(256) void scan_p2_kernel(
    const float* __restrict__ Pbuf, const float* __restrict__ Hend,
    float* __restrict__ Hin) {
  const int i = blockIdx.x * 256 + threadIdx.x;
  const int s = i & (NDS - 1);
  const int c = (i >> 4) & (NDI - 1);
  const int b = i >> 15;
  const size_t step = (size_t)NDI * NDS;
  const size_t base = scoff(b, 0, c) + s;
  float h = 0.f;
  #pragma unroll 8
  for (int k = 0; k < CCH; ++k) {
    Hin[base + (size_t)k * step] = h;
    h = Hend[base + (size_t)k * step] + Pbuf[base + (size_t)k * step] * h;
  }
}

// ---------------------------------------------------------------------------
// phase 3 + merge: rescan; y = (sum_s h + u*D) * silu(z); u,delta from FG
// bf16; z from bf16 xz; LDS slab-transpose -> FG bf16 output.
__global__ __launch_bounds__(256) void scan_p3_kernel(
    const short* __restrict__ dbf, const float* __restrict__ Bm,
    const short* __restrict__ xhbf, const float* __restrict__ A_log,
    const float* __restrict__ Hin, const float* __restrict__ Dvec,
    const short* __restrict__ xz, short* __restrict__ ybf) {
  const int tid = threadIdx.x;
  const int i = blockIdx.x * 256 + tid;
  const int c = i & (NDI - 1);
  const int k = (i >> 11) & (CCH - 1);
  const int b = i >> 16;
  const int t0 = k * CLEN;
  const int cb0 = (blockIdx.x * 256) & (NDI - 1);

  __shared__ float ylds[16][257];

  float Av[NDS];
  #pragma unroll
  for (int s = 0; s < NDS; ++s) Av[s] = -__expf(A_log[c * NDS + s]);
  const float dcoef = Dvec[c];

  const size_t fgb = (size_t)((b * NL + t0) >> 4) * (NDI * 16) +
                     (size_t)(c >> 3) * 128 + (c & 7);
  const short* up = xhbf + fgb;
  const short* dp = dbf + fgb;
  const f32x4* Bp = (const f32x4*)(Bm + ((size_t)(b * NL + t0)) * NDS);
  const short* zp = xz + ((size_t)(b * NL + t0)) * (2 * NDI) + NDI + c;

  const size_t base = scoff(b, k, c);
  float h[NDS];
  #pragma unroll
  for (int s = 0; s < NDS; ++s) h[s] = Hin[base + s];

  for (int j = 0; j < CLEN; ++j) {
    const size_t o = (size_t)(j >> 4) * (NDI * 16) + (j & 15) * 8;
    const float d = bf2f(dp[o]);
    const float u = bf2f(up[o]);
    f32x4 B0 = Bp[j * 4 + 0], B1 = Bp[j * 4 + 1];
    f32x4 B2 = Bp[j * 4 + 2], B3 = Bp[j * 4 + 3];
    const float du = d * u;
    float Bv[NDS];
    #pragma unroll
    for (int e = 0; e < 4; ++e) {
      Bv[e] = B0[e]; Bv[4 + e] = B1[e]; Bv[8 + e] = B2[e]; Bv[12 + e] = B3[e];
    }
    #pragma unroll
    for (int s = 0; s < NDS; ++s) {
      float dA = __expf(d * Av[s]);
      h[s] = dA * h[s] + du * Bv[s];
    }
    float sum01 = 0.f, sum23 = 0.f;
    #pragma unroll
    for (int s = 0; s < 8; ++s)  sum01 += h[s];
    #pragma unroll
    for (int s = 8; s < 16; ++s) sum23 += h[s];
    float y = sum01 + sum23 + u * dcoef;
    float z = bf2f(zp[(size_t)j * (2 * NDI)]);
    y *= z / (1.f + __expf(-z));
    ylds[j & 15][tid] = y;

    if ((j & 15) == 15) {
      __syncthreads();
      const int jb = j - 15;
      #pragma unroll
      for (int s2 = 0; s2 < 2; ++s2) {
        int u2 = tid + 256 * s2;
        int tt = u2 & 15, q = u2 >> 4;
        short8 v;
        #pragma unroll
        for (int e = 0; e < 8; ++e) v[e] = f2bf(ylds[tt][q * 8 + e]);
        int grow = b * NL + t0 + jb + tt;
        int k8 = (cb0 >> 3) + q;
        *(short8*)&ybf[fgoff(grow, k8, NDI)] = v;
      }
      __syncthreads();
    }
  }
}

// ---------------------------------------------------------------------------
extern "C" void kernel_launch(void* const* d_in, const int* in_sizes, int n_in,
                              void* d_out, int out_size, void* d_ws, size_t ws_size,
                              hipStream_t stream) {
  const float* x      = (const float*)d_in[0];
  const float* W_in   = (const float*)d_in[1];
  const float* b_in   = (const float*)d_in[2];
  const float* conv_w = (const float*)d_in[3];
  const float* conv_b = (const float*)d_in[4];
  const float* W_x    = (const float*)d_in[5];
  const float* b_x    = (const float*)d_in[6];
  const float* W_dt   = (const float*)d_in[7];
  const float* b_dt   = (const float*)d_in[8];
  const float* A_log  = (const float*)d_in[9];
  const float* Dv     = (const float*)d_in[10];
  const float* W_out  = (const float*)d_in[11];
  const float* b_out  = (const float*)d_in[12];
  float* out = (float*)d_out;

  char* w = (char*)d_ws;
  short* xbf   = (short*)(w);                  // FG 4096x1024 bf16   8.39MB
  short* WtIn  = (short*)(w + 8388608);        // FG 4096x1024 bf16   8.39MB
  short* WtCat = (short*)(w + 16777216);       // FG 2176x2048 bf16   8.91MB
  short* WtOut = (short*)(w + 25690112);       // FG 1024x2048 bf16   4.19MB
  short* xzbf  = (short*)(w + 29884416);       // 4096x4096 bf16     33.55MB
  short* xhbf  = (short*)(w + 96993280);       // FG 4096x2048 bf16  16.78MB
  short* dbf   = (short*)(w + 113770496);      // FG 4096x2048 bf16  16.78MB
  float* Bm    = (float*)(w + 147324928);      // 4096x16   f32       0.26MB
  short* ybf   = (short*)(w + 147587072);      // FG 4096x2048 bf16  16.78MB
  // scan scratch aliases buffers dead by scan time (8.39MB each):
  float* Pbuf  = (float*)(w);                  // aliases xbf
  float* Hend  = (float*)(w + 8388608);        // aliases WtIn
  float* Hin   = (float*)(w + 16777216);       // aliases WtCat head

  // 0) zero Wcat pad groups 129..135 (rows 2064..2175) once per call
  hipMemsetAsync((char*)WtCat + (size_t)129 * 65536, 0, 7 * 65536, stream);

  // 1) converts / weight transposes into FG layout
  cvt_fg_kernel<<<MROWS / 16, 256, 0, stream>>>(x, xbf);
  transpose_fg_kernel<<<dim3((2 * NDI) / 32, NDM / 64), dim3(32, 8), 0, stream>>>(
      W_in, WtIn, NDM, 2 * NDI);
  transpose_fg_kernel<<<dim3(NDI / 32, NDI / 64), dim3(32, 8), 0, stream>>>(
      W_dt, WtCat, NDI, NDI);
  wx_fg_kernel<<<16, 256, 0, stream>>>(W_x, WtCat);
  transpose_fg_kernel<<<dim3(NDM / 32, NDI / 64), dim3(32, 8), 0, stream>>>(
      W_out, WtOut, NDI, NDM);

  // 2) xz = x @ W_in + b_in -> bf16 row-major (EPI=2; 64x32 = 2048 blocks)
  gemm_fg_kernel<64, 2><<<dim3((2 * NDI) / 64, MROWS / 128), 256, 0, stream>>>(
      xbf, WtIn, b_in, nullptr, xzbf, nullptr, nullptr,
      MROWS, 2 * NDI, NDM);

  // 3) depthwise conv + silu (reads bf16 xz; writes xhbf FG only)
  conv_silu_kernel<<<dim3(NDI / 512, MROWS / 16), 256, 0, stream>>>(
      xzbf, conv_w, conv_b, xhbf);

  // 4+5) fused: [delta(bf16 FG) | Bmat] = xh @ [W_dt | W_x[:,16:32]]
  //      (BN=64: 34x32 = 1088 blocks, 4.25/CU)
  gemm_fg_kernel<64, 1><<<dim3(2176 / 64, MROWS / 128), 256, 0, stream>>>(
      xhbf, WtCat, b_dt, nullptr, dbf, Bm, b_x,
      MROWS, NDI, NDI);

  // 6) selective scan (chunked: local scan -> chunk combine -> rescan+merge)
  scan_p1_kernel<<<(NB * NDI * CCH) / 256, 256, 0, stream>>>(
      dbf, Bm, xhbf, A_log, Pbuf, Hend);
  scan_p2_kernel<<<(NB * NDI * NDS) / 256, 256, 0, stream>>>(Pbuf, Hend, Hin);
  scan_p3_kernel<<<(NB * NDI * CCH) / 256, 256, 0, stream>>>(
      dbf, Bm, xhbf, A_log, Hin, Dv, xzbf, ybf);

  // 7) out = y @ W_out + b_out  (EPI=0, BN=64; 16x32 = 512 blocks)
  gemm_fg_kernel<64, 0><<<dim3(NDM / 64, MROWS / 128), 256, 0, stream>>>(
      ybf, WtOut, b_out, out, nullptr, nullptr, nullptr,
      MROWS, NDM, NDI);
}

// Round 18
// 319.534 us; speedup vs baseline: 1.0542x; 1.0542x over previous
//
#include <hip/hip_runtime.h>
#include <stdint.h>

// Problem constants
#define NDM   1024   // D_MODEL
#define NDS   16     // D_STATE
#define NDC   4      // D_CONV
#define NDI   2048   // D_INNER
#define NB    2      // BATCH
#define NL    2048   // SEQ
#define MROWS (NB*NL)   // 4096
#define CCH   32     // scan chunks
#define CLEN  64     // NL / CCH

typedef __bf16 bf16x8 __attribute__((ext_vector_type(8)));
typedef float  f32x4  __attribute__((ext_vector_type(4)));
typedef short  short8 __attribute__((ext_vector_type(8)));

__device__ __forceinline__ short f2bf(float f) {
  union { float f; unsigned u; } x; x.f = f;
  unsigned r = (x.u + 0x7FFFu + ((x.u >> 16) & 1u)) >> 16;
  return (short)r;
}
__device__ __forceinline__ float bf2f(short s) {
  union { unsigned u; float f; } x; x.u = ((unsigned)(unsigned short)s) << 16;
  return x.f;
}

// Fragment-order Global layout (FG): 16-row groups; chunk (k8, r) of 8 shorts
// at k8*128 + (r&15)*8. A 16x32 MFMA fragment = CONTIGUOUS 1KB in lane order.
__device__ __forceinline__ size_t fgoff(int row, int k8, int K) {
  return (size_t)(row >> 4) * K * 16 + (size_t)k8 * 128 + (row & 15) * 8;
}

__device__ __forceinline__ void gload16(const void* g, void* l) {
  __builtin_amdgcn_global_load_lds(
      (__attribute__((address_space(1))) void*)(uintptr_t)g,
      (__attribute__((address_space(3))) void*)l,
      16, 0, 0);
}

// ---------------------------------------------------------------------------
// x (f32, MROWS x 1024 row-major) -> FG bf16 via LDS slab
__global__ __launch_bounds__(256) void cvt_fg_kernel(
    const float* __restrict__ in, short* __restrict__ out) {
  __shared__ short slab[16][1032];
  const int tid = threadIdx.x;
  const int g = blockIdx.x;
  const float* p = in + (size_t)g * 16 * 1024;
  #pragma unroll
  for (int u = 0; u < 8; ++u) {
    int unit = u * 256 + tid;
    int rr = unit >> 7, cc = unit & 127;
    const float* rp = p + (size_t)rr * 1024 + cc * 8;
    #pragma unroll
    for (int e = 0; e < 8; ++e) slab[rr][cc * 8 + e] = f2bf(rp[e]);
  }
  __syncthreads();
  short* op = out + (size_t)g * 16384;
  #pragma unroll
  for (int u = 0; u < 8; ++u) {
    int u2 = u * 256 + tid;
    int rr = u2 & 15, k8 = u2 >> 4;
    *(short8*)&op[k8 * 128 + rr * 8] = *(short8*)&slab[rr][k8 * 8];
  }
}

// ---------------------------------------------------------------------------
// W (K x N f32) -> FG bf16 of W^T (N rows, K cols). 32n x 64k tiles.
__global__ __launch_bounds__(256) void transpose_fg_kernel(
    const float* __restrict__ in, short* __restrict__ out, int K, int N) {
  __shared__ float t[64][33];
  const int tx = threadIdx.x, ty = threadIdx.y;   // 32, 8
  const int n0 = blockIdx.x * 32, k0 = blockIdx.y * 64;
  #pragma unroll
  for (int i = 0; i < 64; i += 8)
    t[ty + i][tx] = in[(size_t)(k0 + ty + i) * N + n0 + tx];
  __syncthreads();
  const int n = n0 + tx, k8 = (k0 >> 3) + ty;
  short8 v;
  #pragma unroll
  for (int e = 0; e < 8; ++e) v[e] = f2bf(t[ty * 8 + e][tx]);
  *(short8*)&out[fgoff(n, k8, K)] = v;
}

// ---------------------------------------------------------------------------
// W_x cols 16..31 -> FG rows 2048..2063 of Wcat (group 128). K=2048.
__global__ __launch_bounds__(256) void wx_fg_kernel(
    const float* __restrict__ Wx, short* __restrict__ Wcat) {
  int t = blockIdx.x * 256 + threadIdx.x;     // 4096 = 256 k8 x 16 n
  int k8 = t >> 4, n = t & 15;
  short8 v;
  #pragma unroll
  for (int e = 0; e < 8; ++e)
    v[e] = f2bf(Wx[(size_t)(k8 * 8 + e) * (2 * NDS) + NDS + n]);
  *(short8*)&Wcat[(size_t)128 * 2048 * 16 + (size_t)k8 * 128 + n * 8] = v;
}

// ---------------------------------------------------------------------------
// FG bf16 TN GEMM, 128xBN tile, ring-3 LDS pipeline with COUNTED vmcnt:
// per K-step: waitcnt(vmcnt=L) [own tile-t loads retired, t+1 in flight]
// -> s_barrier -> sched_barrier -> stage tile t+2 -> ds_read + MFMA(setprio).
// FG staging: every gload16 is a contiguous 1KB fragment (no scatter — the
// confound that nulled the R6/R7 schedule experiments).
// EPI=0: f32 C + bias (gemm-out)
// EPI=1: delta = softplus(v+bias) -> bf16 FG via LDS ctile; col 2048 -> Bm
// EPI=2: bf16 row-major C via LDS ctile (xz output)
template<int BN, int EPI>
__global__ __launch_bounds__(256, 3) void gemm_fg_kernel(
    const short* __restrict__ A, const short* __restrict__ Bt,
    const float* __restrict__ bias, float* __restrict__ C,
    short* __restrict__ Cb, float* __restrict__ Bm,
    const float* __restrict__ bx, int M, int N, int K)
{
  const int tid  = threadIdx.x;
  const int lane = tid & 63;
  const int w    = tid >> 6;      // wave 0..3
  const int wM   = w >> 1;
  const int wN   = w & 1;
  const int g    = lane >> 4;
  const int r    = lane & 15;

  constexpr int FN   = BN / 32;       // N fragments per wave (4 or 2)
  constexpr int BTS  = BN * 32;       // B tile shorts
  constexpr int SLOT = 4096 + BTS;    // ring slot shorts (A tile + B tile)
  constexpr int STG  = 3 * SLOT;
  constexpr int CTS  = BN + 8;        // ctile stride
  constexpr int POOL = (EPI != 0 && STG < 128 * CTS) ? 128 * CTS : STG;
  __shared__ short pool[POOL];

  // XCD-aware swizzle (all grids have nwg % 8 == 0)
  const int nx  = gridDim.x;
  const int nwg = nx * gridDim.y;
  const int bid = blockIdx.y * nx + blockIdx.x;
  const int swz = (bid & 7) * (nwg >> 3) + (bid >> 3);
  const int bm  = (swz / nx) * 128;
  const int bn  = (swz % nx) * BN;

  // staging pointers: wave w stages A groups {2w,2w+1}; B groups {2w,2w+1}
  // (BN=128) or group w (BN=64). Each gload16 = contiguous 1KB fragment.
  const short* pA[2];
  #pragma unroll
  for (int q = 0; q < 2; ++q)
    pA[q] = A + (size_t)((bm >> 4) + 2 * w + q) * K * 16 + lane * 8;
  const short* pB[2];
  if constexpr (BN == 128) {
    #pragma unroll
    for (int q = 0; q < 2; ++q)
      pB[q] = Bt + (size_t)((bn >> 4) + 2 * w + q) * K * 16 + lane * 8;
  } else {
    pB[0] = Bt + (size_t)((bn >> 4) + w) * K * 16 + lane * 8;
    pB[1] = pB[0];
  }

#define STAGE(buf, kb)                                                      \
  do {                                                                      \
    _Pragma("unroll")                                                       \
    for (int q = 0; q < 2; ++q)                                             \
      gload16(pA[q] + (size_t)(kb) * 16,                                    \
              pool + (buf) * SLOT + (2 * w + q) * 512);                     \
    if constexpr (BN == 128) {                                              \
      _Pragma("unroll")                                                     \
      for (int q = 0; q < 2; ++q)                                           \
        gload16(pB[q] + (size_t)(kb) * 16,                                  \
                pool + (buf) * SLOT + 4096 + (2 * w + q) * 512);            \
    } else {                                                                \
      gload16(pB[0] + (size_t)(kb) * 16,                                    \
              pool + (buf) * SLOT + 4096 + w * 512);                        \
    }                                                                       \
  } while (0)

  f32x4 acc[4][FN];
  #pragma unroll
  for (int m = 0; m < 4; ++m)
    #pragma unroll
    for (int n = 0; n < FN; ++n)
      acc[m][n] = (f32x4){0.f, 0.f, 0.f, 0.f};

  const int NT = K >> 5;          // BK=32 steps
  STAGE(0, 0);
  STAGE(1, 32);
  int cur = 0;
  for (int t = 0; t < NT; ++t) {
    if (t < NT - 1) {
      if constexpr (BN == 128)
        asm volatile("s_waitcnt vmcnt(4)" ::: "memory");
      else
        asm volatile("s_waitcnt vmcnt(3)" ::: "memory");
    } else {
      asm volatile("s_waitcnt vmcnt(0)" ::: "memory");
    }
    __builtin_amdgcn_s_barrier();          // tile t visible to all waves
    __builtin_amdgcn_sched_barrier(0);     // no motion across the barrier
    if (t + 2 < NT) STAGE((t + 2) % 3, (t + 2) * 32);  // refill (t-1)%3

    bf16x8 af[4], bfv[FN];
    #pragma unroll
    for (int m = 0; m < 4; ++m)
      af[m] = *(const bf16x8*)(pool + cur * SLOT + (wM * 4 + m) * 512 + lane * 8);
    #pragma unroll
    for (int n = 0; n < FN; ++n)
      bfv[n] = *(const bf16x8*)(pool + cur * SLOT + 4096 +
                                (wN * FN + n) * 512 + lane * 8);
    __builtin_amdgcn_s_setprio(1);
    #pragma unroll
    for (int m = 0; m < 4; ++m)
      #pragma unroll
      for (int n = 0; n < FN; ++n)
        acc[m][n] = __builtin_amdgcn_mfma_f32_16x16x32_bf16(
            af[m], bfv[n], acc[m][n], 0, 0, 0);
    __builtin_amdgcn_s_setprio(0);
    cur = (cur + 1 == 3) ? 0 : cur + 1;
  }
#undef STAGE

  // D layout (verified m89/m91): col = lane&15, row = (lane>>4)*4 + e
  if constexpr (EPI == 2) {
    __syncthreads();                 // all waves done with pool -> ctile
    short (*ctile)[CTS] = (short(*)[CTS])pool;
    #pragma unroll
    for (int m = 0; m < 4; ++m) {
      const int rl0 = wM * 64 + m * 16 + g * 4;
      #pragma unroll
      for (int n = 0; n < FN; ++n) {
        const int cl = wN * (BN / 2) + n * 16 + r;
        const float bv = bias[bn + cl];
        #pragma unroll
        for (int e = 0; e < 4; ++e)
          ctile[rl0 + e][cl] = f2bf(acc[m][n][e] + bv);
      }
    }
    __syncthreads();
    #pragma unroll
    for (int it = 0; it < (128 * BN / 8) / 256; ++it) {
      int id = it * 256 + tid;
      int rowL = id / (BN / 8), c8 = id % (BN / 8);
      *(short8*)&Cb[(size_t)(bm + rowL) * N + bn + c8 * 8] =
          *(short8*)&ctile[rowL][c8 * 8];
    }
  } else if constexpr (EPI == 1) {
    __syncthreads();
    short (*ctile)[CTS] = (short(*)[CTS])pool;
    #pragma unroll
    for (int m = 0; m < 4; ++m) {
      const int rl0 = wM * 64 + m * 16 + g * 4;
      const int row0 = bm + rl0;
      #pragma unroll
      for (int n = 0; n < FN; ++n) {
        const int colbase = bn + wN * (BN / 2) + n * 16;
        if (colbase < 2048) {
          const int cl = wN * (BN / 2) + n * 16 + r;
          const float bv = bias[colbase + r];
          #pragma unroll
          for (int e = 0; e < 4; ++e) {
            float v = acc[m][n][e] + bv;
            v = (v > 15.f) ? v : log1pf(__expf(v));
            ctile[rl0 + e][cl] = f2bf(v);
          }
        } else if (colbase == 2048) {
          const float bv = bx[NDS + r];
          #pragma unroll
          for (int e = 0; e < 4; ++e)
            Bm[(size_t)(row0 + e) * NDS + r] = acc[m][n][e] + bv;
        }
      }
    }
    __syncthreads();
    if (bn < 2048) {
      // drain 128xBN ctile into FG (rr-minor -> contiguous 16B chunks)
      constexpr int CH = 2 * BN;          // units per 16-row group
      #pragma unroll
      for (int it = 0; it < (8 * CH) / 256; ++it) {
        int unit = it * 256 + tid;
        int grp = unit / CH, wi = unit % CH;
        int k8l = wi >> 4, rr = wi & 15;
        *(short8*)&Cb[(size_t)((bm >> 4) + grp) * (NDI * 16) +
                      (size_t)((bn >> 3) + k8l) * 128 + rr * 8] =
            *(short8*)&ctile[grp * 16 + rr][k8l * 8];
      }
    }
  } else {
    #pragma unroll
    for (int m = 0; m < 4; ++m) {
      const int row0 = bm + wM * 64 + m * 16 + g * 4;
      #pragma unroll
      for (int n = 0; n < FN; ++n) {
        const int col = bn + wN * (BN / 2) + n * 16 + r;
        const float bv = bias[col];
        #pragma unroll
        for (int e = 0; e < 4; ++e)
          C[(size_t)(row0 + e) * N + col] = acc[m][n][e] + bv;
      }
    }
  }
}

// ---------------------------------------------------------------------------
// depthwise causal conv (width 4) + bias + SiLU; reads bf16 xz;
// writes ONLY xhbf (FG bf16) via slab.
__global__ __launch_bounds__(256) void conv_silu_kernel(
    const short* __restrict__ xz, const float* __restrict__ cw,
    const float* __restrict__ cb, short* __restrict__ xhbf) {
  __shared__ short slab[16][528];
  const int tid = threadIdx.x;
  const int c0 = blockIdx.x * 512;
  const int r0 = blockIdx.y * 16;
  const int b  = r0 >> 11;
  const int t0 = r0 & (NL - 1);
  const short* zbase = xz + ((size_t)b * NL) * (2 * NDI);

  #pragma unroll
  for (int u = 0; u < 4; ++u) {
    int unit = u * 256 + tid;
    int rr = unit >> 6, cc = unit & 63;
    int t = t0 + rr, c = c0 + cc * 8;
    float acc[8];
    #pragma unroll
    for (int e = 0; e < 8; ++e) acc[e] = cb[c + e];
    #pragma unroll
    for (int k = 0; k < NDC; ++k) {
      int tt = t - (NDC - 1) + k;
      if (tt >= 0) {
        short8 rv = *(const short8*)(zbase + (size_t)tt * (2 * NDI) + c);
        #pragma unroll
        for (int e = 0; e < 8; ++e)
          acc[e] += cw[(c + e) * NDC + k] * bf2f(rv[e]);
      }
    }
    #pragma unroll
    for (int e = 0; e < 8; ++e) {
      float s = acc[e] / (1.f + __expf(-acc[e]));
      slab[rr][cc * 8 + e] = f2bf(s);
    }
  }
  __syncthreads();
  short* op = xhbf + (size_t)(r0 >> 4) * NDI * 16 + (size_t)(c0 >> 3) * 128;
  #pragma unroll
  for (int u = 0; u < 4; ++u) {
    int u2 = u * 256 + tid;
    int rr = u2 & 15, q = u2 >> 4;
    *(short8*)&op[q * 128 + rr * 8] = *(short8*)&slab[rr][q * 8];
  }
}

// ---------------------------------------------------------------------------
// scan scratch layout: [b][k][c][s]
__device__ __forceinline__ size_t scoff(int b, int k, int c) {
  return (((size_t)b * CCH + k) * NDI + c) * NDS;
}

// phase 1: thread = (b, c, chunk); 16 states in registers; u,d from FG bf16.
__global__ __launch_bounds__(256) void scan_p1_kernel(
    const short* __restrict__ dbf, const float* __restrict__ Bm,
    const short* __restrict__ xhbf, const float* __restrict__ A_log,
    float* __restrict__ Pbuf, float* __restrict__ Hend) {
  const int i = blockIdx.x * 256 + threadIdx.x;
  const int c = i & (NDI - 1);
  const int k = (i >> 11) & (CCH - 1);
  const int b = i >> 16;
  const int t0 = k * CLEN;

  float Av[NDS];
  #pragma unroll
  for (int s = 0; s < NDS; ++s) Av[s] = -__expf(A_log[c * NDS + s]);

  const size_t fgb = (size_t)((b * NL + t0) >> 4) * (NDI * 16) +
                     (size_t)(c >> 3) * 128 + (c & 7);
  const short* up = xhbf + fgb;
  const short* dp = dbf + fgb;
  const f32x4* Bp = (const f32x4*)(Bm + ((size_t)(b * NL + t0)) * NDS);

  float h[NDS], P[NDS];
  #pragma unroll
  for (int s = 0; s < NDS; ++s) { h[s] = 0.f; P[s] = 1.f; }

  #pragma unroll 4
  for (int j = 0; j < CLEN; ++j) {
    const size_t o = (size_t)(j >> 4) * (NDI * 16) + (j & 15) * 8;
    const float d = bf2f(dp[o]);
    const float u = bf2f(up[o]);
    f32x4 B0 = Bp[j * 4 + 0], B1 = Bp[j * 4 + 1];
    f32x4 B2 = Bp[j * 4 + 2], B3 = Bp[j * 4 + 3];
    const float du = d * u;
    float Bv[NDS];
    #pragma unroll
    for (int e = 0; e < 4; ++e) {
      Bv[e] = B0[e]; Bv[4 + e] = B1[e]; Bv[8 + e] = B2[e]; Bv[12 + e] = B3[e];
    }
    #pragma unroll
    for (int s = 0; s < NDS; ++s) {
      float dA = __expf(d * Av[s]);
      h[s] = dA * h[s] + du * Bv[s];
      P[s] *= dA;
    }
  }

  const size_t base = scoff(b, k, c);
  #pragma unroll
  for (int q = 0; q < 4; ++q) {
    *(f32x4*)&Pbuf[base + q * 4] = (f32x4){P[q*4], P[q*4+1], P[q*4+2], P[q*4+3]};
    *(f32x4*)&Hend[base + q * 4] = (f32x4){h[q*4], h[q*4+1], h[q*4+2], h[q*4+3]};
  }
}

// ---------------------------------------------------------------------------
// phase 2: thread = (b, c, s); serial combine across the chunks.
__global__ __launch_bounds__(256) void scan_p2_kernel(
    const float* __restrict__ Pbuf, const float* __restrict__ Hend,
    float* __restrict__ Hin) {
  const int i = blockIdx.x * 256 + threadIdx.x;
  const int s = i & (NDS - 1);
  const int c = (i >> 4) & (NDI - 1);
  const int b = i >> 15;
  const size_t step = (size_t)NDI * NDS;
  const size_t base = scoff(b, 0, c) + s;
  float h = 0.f;
  #pragma unroll 8
  for (int k = 0; k < CCH; ++k) {
    Hin[base + (size_t)k * step] = h;
    h = Hend[base + (size_t)k * step] + Pbuf[base + (size_t)k * step] * h;
  }
}

// ---------------------------------------------------------------------------
// phase 3 + merge: rescan; y = (sum_s h + u*D) * silu(z); u,delta from FG
// bf16; z from bf16 xz; LDS slab-transpose -> FG bf16 output.
__global__ __launch_bounds__(256) void scan_p3_kernel(
    const short* __restrict__ dbf, const float* __restrict__ Bm,
    const short* __restrict__ xhbf, const float* __restrict__ A_log,
    const float* __restrict__ Hin, const float* __restrict__ Dvec,
    const short* __restrict__ xz, short* __restrict__ ybf) {
  const int tid = threadIdx.x;
  const int i = blockIdx.x * 256 + tid;
  const int c = i & (NDI - 1);
  const int k = (i >> 11) & (CCH - 1);
  const int b = i >> 16;
  const int t0 = k * CLEN;
  const int cb0 = (blockIdx.x * 256) & (NDI - 1);

  __shared__ float ylds[16][257];

  float Av[NDS];
  #pragma unroll
  for (int s = 0; s < NDS; ++s) Av[s] = -__expf(A_log[c * NDS + s]);
  const float dcoef = Dvec[c];

  const size_t fgb = (size_t)((b * NL + t0) >> 4) * (NDI * 16) +
                     (size_t)(c >> 3) * 128 + (c & 7);
  const short* up = xhbf + fgb;
  const short* dp = dbf + fgb;
  const f32x4* Bp = (const f32x4*)(Bm + ((size_t)(b * NL + t0)) * NDS);
  const short* zp = xz + ((size_t)(b * NL + t0)) * (2 * NDI) + NDI + c;

  const size_t base = scoff(b, k, c);
  float h[NDS];
  #pragma unroll
  for (int s = 0; s < NDS; ++s) h[s] = Hin[base + s];

  for (int j = 0; j < CLEN; ++j) {
    const size_t o = (size_t)(j >> 4) * (NDI * 16) + (j & 15) * 8;
    const float d = bf2f(dp[o]);
    const float u = bf2f(up[o]);
    f32x4 B0 = Bp[j * 4 + 0], B1 = Bp[j * 4 + 1];
    f32x4 B2 = Bp[j * 4 + 2], B3 = Bp[j * 4 + 3];
    const float du = d * u;
    float Bv[NDS];
    #pragma unroll
    for (int e = 0; e < 4; ++e) {
      Bv[e] = B0[e]; Bv[4 + e] = B1[e]; Bv[8 + e] = B2[e]; Bv[12 + e] = B3[e];
    }
    #pragma unroll
    for (int s = 0; s < NDS; ++s) {
      float dA = __expf(d * Av[s]);
      h[s] = dA * h[s] + du * Bv[s];
    }
    float sum01 = 0.f, sum23 = 0.f;
    #pragma unroll
    for (int s = 0; s < 8; ++s)  sum01 += h[s];
    #pragma unroll
    for (int s = 8; s < 16; ++s) sum23 += h[s];
    float y = sum01 + sum23 + u * dcoef;
    float z = bf2f(zp[(size_t)j * (2 * NDI)]);
    y *= z / (1.f + __expf(-z));
    ylds[j & 15][tid] = y;

    if ((j & 15) == 15) {
      __syncthreads();
      const int jb = j - 15;
      #pragma unroll
      for (int s2 = 0; s2 < 2; ++s2) {
        int u2 = tid + 256 * s2;
        int tt = u2 & 15, q = u2 >> 4;
        short8 v;
        #pragma unroll
        for (int e = 0; e < 8; ++e) v[e] = f2bf(ylds[tt][q * 8 + e]);
        int grow = b * NL + t0 + jb + tt;
        int k8 = (cb0 >> 3) + q;
        *(short8*)&ybf[fgoff(grow, k8, NDI)] = v;
      }
      __syncthreads();
    }
  }
}

// ---------------------------------------------------------------------------
extern "C" void kernel_launch(void* const* d_in, const int* in_sizes, int n_in,
                              void* d_out, int out_size, void* d_ws, size_t ws_size,
                              hipStream_t stream) {
  const float* x      = (const float*)d_in[0];
  const float* W_in   = (const float*)d_in[1];
  const float* b_in   = (const float*)d_in[2];
  const float* conv_w = (const float*)d_in[3];
  const float* conv_b = (const float*)d_in[4];
  const float* W_x    = (const float*)d_in[5];
  const float* b_x    = (const float*)d_in[6];
  const float* W_dt   = (const float*)d_in[7];
  const float* b_dt   = (const float*)d_in[8];
  const float* A_log  = (const float*)d_in[9];
  const float* Dv     = (const float*)d_in[10];
  const float* W_out  = (const float*)d_in[11];
  const float* b_out  = (const float*)d_in[12];
  float* out = (float*)d_out;

  char* w = (char*)d_ws;
  short* xbf   = (short*)(w);                  // FG 4096x1024 bf16   8.39MB
  short* WtIn  = (short*)(w + 8388608);        // FG 4096x1024 bf16   8.39MB
  short* WtCat = (short*)(w + 16777216);       // FG 2176x2048 bf16   8.91MB
  short* WtOut = (short*)(w + 25690112);       // FG 1024x2048 bf16   4.19MB
  short* xzbf  = (short*)(w + 29884416);       // 4096x4096 bf16     33.55MB
  short* xhbf  = (short*)(w + 96993280);       // FG 4096x2048 bf16  16.78MB
  short* dbf   = (short*)(w + 113770496);      // FG 4096x2048 bf16  16.78MB
  float* Bm    = (float*)(w + 147324928);      // 4096x16   f32       0.26MB
  short* ybf   = (short*)(w + 147587072);      // FG 4096x2048 bf16  16.78MB
  // scan scratch aliases buffers dead by scan time (8.39MB each):
  float* Pbuf  = (float*)(w);                  // aliases xbf
  float* Hend  = (float*)(w + 8388608);        // aliases WtIn
  float* Hin   = (float*)(w + 16777216);       // aliases WtCat head

  // 0) zero Wcat pad groups 129..135 (rows 2064..2175) once per call
  hipMemsetAsync((char*)WtCat + (size_t)129 * 65536, 0, 7 * 65536, stream);

  // 1) converts / weight transposes into FG layout
  cvt_fg_kernel<<<MROWS / 16, 256, 0, stream>>>(x, xbf);
  transpose_fg_kernel<<<dim3((2 * NDI) / 32, NDM / 64), dim3(32, 8), 0, stream>>>(
      W_in, WtIn, NDM, 2 * NDI);
  transpose_fg_kernel<<<dim3(NDI / 32, NDI / 64), dim3(32, 8), 0, stream>>>(
      W_dt, WtCat, NDI, NDI);
  wx_fg_kernel<<<16, 256, 0, stream>>>(W_x, WtCat);
  transpose_fg_kernel<<<dim3(NDM / 32, NDI / 64), dim3(32, 8), 0, stream>>>(
      W_out, WtOut, NDI, NDM);

  // 2) xz = x @ W_in + b_in -> bf16 row-major (EPI=2; 32x32 = 1024 blocks)
  gemm_fg_kernel<128, 2><<<dim3((2 * NDI) / 128, MROWS / 128), 256, 0, stream>>>(
      xbf, WtIn, b_in, nullptr, xzbf, nullptr, nullptr,
      MROWS, 2 * NDI, NDM);

  // 3) depthwise conv + silu (reads bf16 xz; writes xhbf FG only)
  conv_silu_kernel<<<dim3(NDI / 512, MROWS / 16), 256, 0, stream>>>(
      xzbf, conv_w, conv_b, xhbf);

  // 4+5) fused: [delta(bf16 FG) | Bmat] = xh @ [W_dt | W_x[:,16:32]]
  //      (BN=128: 17x32 = 544 blocks)
  gemm_fg_kernel<128, 1><<<dim3(2176 / 128, MROWS / 128), 256, 0, stream>>>(
      xhbf, WtCat, b_dt, nullptr, dbf, Bm, b_x,
      MROWS, NDI, NDI);

  // 6) selective scan (chunked: local scan -> chunk combine -> rescan+merge)
  scan_p1_kernel<<<(NB * NDI * CCH) / 256, 256, 0, stream>>>(
      dbf, Bm, xhbf, A_log, Pbuf, Hend);
  scan_p2_kernel<<<(NB * NDI * NDS) / 256, 256, 0, stream>>>(Pbuf, Hend, Hin);
  scan_p3_kernel<<<(NB * NDI * CCH) / 256, 256, 0, stream>>>(
      dbf, Bm, xhbf, A_log, Hin, Dv, xzbf, ybf);

  // 7) out = y @ W_out + b_out  (EPI=0, BN=64; 16x32 = 512 blocks)
  gemm_fg_kernel<64, 0><<<dim3(NDM / 64, MROWS / 128), 256, 0, stream>>>(
      ybf, WtOut, b_out, out, nullptr, nullptr, nullptr,
      MROWS, NDM, NDI);
}

// Round 19
// 315.250 us; speedup vs baseline: 1.0686x; 1.0136x over previous
//
#include <hip/hip_runtime.h>
#include <stdint.h>

// Problem constants
#define NDM   1024   // D_MODEL
#define NDS   16     // D_STATE
#define NDC   4      // D_CONV
#define NDI   2048   // D_INNER
#define NB    2      // BATCH
#define NL    2048   // SEQ
#define MROWS (NB*NL)   // 4096
#define CCH   32     // scan chunks
#define CLEN  64     // NL / CCH

typedef __bf16 bf16x8 __attribute__((ext_vector_type(8)));
typedef float  f32x4  __attribute__((ext_vector_type(4)));
typedef short  short8 __attribute__((ext_vector_type(8)));

__device__ __forceinline__ short f2bf(float f) {
  union { float f; unsigned u; } x; x.f = f;
  unsigned r = (x.u + 0x7FFFu + ((x.u >> 16) & 1u)) >> 16;
  return (short)r;
}
__device__ __forceinline__ float bf2f(short s) {
  union { unsigned u; float f; } x; x.u = ((unsigned)(unsigned short)s) << 16;
  return x.f;
}

// Fragment-order Global layout (FG): 16-row groups; chunk (k8, r) of 8 shorts
// at k8*128 + (r&15)*8. A 16x32 MFMA fragment = CONTIGUOUS 1KB in lane order.
__device__ __forceinline__ size_t fgoff(int row, int k8, int K) {
  return (size_t)(row >> 4) * K * 16 + (size_t)k8 * 128 + (row & 15) * 8;
}

__device__ __forceinline__ void gload16(const void* g, void* l) {
  __builtin_amdgcn_global_load_lds(
      (__attribute__((address_space(1))) void*)(uintptr_t)g,
      (__attribute__((address_space(3))) void*)l,
      16, 0, 0);
}

// ---------------------------------------------------------------------------
// x (f32, MROWS x 1024 row-major) -> FG bf16 via LDS slab
__global__ __launch_bounds__(256) void cvt_fg_kernel(
    const float* __restrict__ in, short* __restrict__ out) {
  __shared__ short slab[16][1032];
  const int tid = threadIdx.x;
  const int g = blockIdx.x;
  const float* p = in + (size_t)g * 16 * 1024;
  #pragma unroll
  for (int u = 0; u < 8; ++u) {
    int unit = u * 256 + tid;
    int rr = unit >> 7, cc = unit & 127;
    const float* rp = p + (size_t)rr * 1024 + cc * 8;
    #pragma unroll
    for (int e = 0; e < 8; ++e) slab[rr][cc * 8 + e] = f2bf(rp[e]);
  }
  __syncthreads();
  short* op = out + (size_t)g * 16384;
  #pragma unroll
  for (int u = 0; u < 8; ++u) {
    int u2 = u * 256 + tid;
    int rr = u2 & 15, k8 = u2 >> 4;
    *(short8*)&op[k8 * 128 + rr * 8] = *(short8*)&slab[rr][k8 * 8];
  }
}

// ---------------------------------------------------------------------------
// W (K x N f32) -> FG bf16 of W^T (N rows, K cols). 32n x 64k tiles.
__global__ __launch_bounds__(256) void transpose_fg_kernel(
    const float* __restrict__ in, short* __restrict__ out, int K, int N) {
  __shared__ float t[64][33];
  const int tx = threadIdx.x, ty = threadIdx.y;   // 32, 8
  const int n0 = blockIdx.x * 32, k0 = blockIdx.y * 64;
  #pragma unroll
  for (int i = 0; i < 64; i += 8)
    t[ty + i][tx] = in[(size_t)(k0 + ty + i) * N + n0 + tx];
  __syncthreads();
  const int n = n0 + tx, k8 = (k0 >> 3) + ty;
  short8 v;
  #pragma unroll
  for (int e = 0; e < 8; ++e) v[e] = f2bf(t[ty * 8 + e][tx]);
  *(short8*)&out[fgoff(n, k8, K)] = v;
}

// ---------------------------------------------------------------------------
// W_x cols 16..31 -> FG rows 2048..2063 of Wcat (group 128). K=2048.
__global__ __launch_bounds__(256) void wx_fg_kernel(
    const float* __restrict__ Wx, short* __restrict__ Wcat) {
  int t = blockIdx.x * 256 + threadIdx.x;     // 4096 = 256 k8 x 16 n
  int k8 = t >> 4, n = t & 15;
  short8 v;
  #pragma unroll
  for (int e = 0; e < 8; ++e)
    v[e] = f2bf(Wx[(size_t)(k8 * 8 + e) * (2 * NDS) + NDS + n]);
  *(short8*)&Wcat[(size_t)128 * 2048 * 16 + (size_t)k8 * 128 + n * 8] = v;
}

// ---------------------------------------------------------------------------
// FG bf16 TN GEMM, 128xBN tile, ring-4 LDS pipeline, counted vmcnt, K and
// ring indices COMPILE-TIME (unroll 4, buf = t&3): all LDS addresses fold to
// base+immediate, staged pointers strength-reduce — kills the 45% VALUBusy
// address-arithmetic overhead measured in R18.
// EPI=0: f32 C + bias (gemm-out)
// EPI=1: delta = softplus(v+bias) -> bf16 FG via LDS ctile; col 2048 -> Bm
// EPI=2: bf16 row-major C via LDS ctile (xz output)
template<int BN, int EPI, int KT>
__global__ __launch_bounds__(256, 2) void gemm_fg_kernel(
    const short* __restrict__ A, const short* __restrict__ Bt,
    const float* __restrict__ bias, float* __restrict__ C,
    short* __restrict__ Cb, float* __restrict__ Bm,
    const float* __restrict__ bx, int M, int N)
{
  const int tid  = threadIdx.x;
  const int lane = tid & 63;
  const int w    = tid >> 6;      // wave 0..3
  const int wM   = w >> 1;
  const int wN   = w & 1;
  const int g    = lane >> 4;
  const int r    = lane & 15;

  constexpr int FN   = BN / 32;       // N fragments per wave (4 or 2)
  constexpr int BTS  = BN * 32;       // B tile shorts
  constexpr int SLOT = 4096 + BTS;    // ring slot shorts (A tile + B tile)
  constexpr int STG  = 4 * SLOT;      // ring-4
  constexpr int CTS  = BN + 8;        // ctile stride
  constexpr int POOL = (EPI != 0 && STG < 128 * CTS) ? 128 * CTS : STG;
  __shared__ short pool[POOL];

  // XCD-aware swizzle (all grids have nwg % 8 == 0)
  const int nx  = gridDim.x;
  const int nwg = nx * gridDim.y;
  const int bid = blockIdx.y * nx + blockIdx.x;
  const int swz = (bid & 7) * (nwg >> 3) + (bid >> 3);
  const int bm  = (swz / nx) * 128;
  const int bn  = (swz % nx) * BN;

  // staging pointers: wave w stages A groups {2w,2w+1}; B groups {2w,2w+1}
  // (BN=128) or group w (BN=64). Each gload16 = contiguous 1KB fragment.
  const short* pA[2];
  #pragma unroll
  for (int q = 0; q < 2; ++q)
    pA[q] = A + (size_t)((bm >> 4) + 2 * w + q) * KT * 16 + lane * 8;
  const short* pB[2];
  if constexpr (BN == 128) {
    #pragma unroll
    for (int q = 0; q < 2; ++q)
      pB[q] = Bt + (size_t)((bn >> 4) + 2 * w + q) * KT * 16 + lane * 8;
  } else {
    pB[0] = Bt + (size_t)((bn >> 4) + w) * KT * 16 + lane * 8;
    pB[1] = pB[0];
  }

#define STAGE(buf, kb)                                                      \
  do {                                                                      \
    _Pragma("unroll")                                                       \
    for (int q = 0; q < 2; ++q)                                             \
      gload16(pA[q] + (size_t)(kb) * 16,                                    \
              pool + (buf) * SLOT + (2 * w + q) * 512);                     \
    if constexpr (BN == 128) {                                              \
      _Pragma("unroll")                                                     \
      for (int q = 0; q < 2; ++q)                                           \
        gload16(pB[q] + (size_t)(kb) * 16,                                  \
                pool + (buf) * SLOT + 4096 + (2 * w + q) * 512);            \
    } else {                                                                \
      gload16(pB[0] + (size_t)(kb) * 16,                                    \
              pool + (buf) * SLOT + 4096 + w * 512);                        \
    }                                                                       \
  } while (0)

  f32x4 acc[4][FN];
  #pragma unroll
  for (int m = 0; m < 4; ++m)
    #pragma unroll
    for (int n = 0; n < FN; ++n)
      acc[m][n] = (f32x4){0.f, 0.f, 0.f, 0.f};

  constexpr int NT = KT >> 5;     // BK=32 steps: 32 or 64 (divisible by 4)
  STAGE(0, 0);
  STAGE(1, 32);
  STAGE(2, 64);

  #pragma unroll 4
  for (int t = 0; t < NT; ++t) {
    // counted vmcnt: retire tile-t loads; keep t+1,t+2 in flight.
    if (t < NT - 2) {
      if constexpr (BN == 128)
        asm volatile("s_waitcnt vmcnt(8)" ::: "memory");
      else
        asm volatile("s_waitcnt vmcnt(6)" ::: "memory");
    } else if (t == NT - 2) {
      if constexpr (BN == 128)
        asm volatile("s_waitcnt vmcnt(4)" ::: "memory");
      else
        asm volatile("s_waitcnt vmcnt(3)" ::: "memory");
    } else {
      asm volatile("s_waitcnt vmcnt(0)" ::: "memory");
    }
    __builtin_amdgcn_s_barrier();          // tile t visible to all waves
    asm volatile("" ::: "memory");         // compiler fence (no codegen)
    if (t + 3 < NT) STAGE((t + 3) & 3, (t + 3) * 32);  // refill (t-1)&3

    const int cb = t & 3;                  // constant per unrolled body
    bf16x8 af[4], bfv[FN];
    #pragma unroll
    for (int m = 0; m < 4; ++m)
      af[m] = *(const bf16x8*)(pool + cb * SLOT + (wM * 4 + m) * 512 + lane * 8);
    #pragma unroll
    for (int n = 0; n < FN; ++n)
      bfv[n] = *(const bf16x8*)(pool + cb * SLOT + 4096 +
                                (wN * FN + n) * 512 + lane * 8);
    __builtin_amdgcn_s_setprio(1);
    #pragma unroll
    for (int m = 0; m < 4; ++m)
      #pragma unroll
      for (int n = 0; n < FN; ++n)
        acc[m][n] = __builtin_amdgcn_mfma_f32_16x16x32_bf16(
            af[m], bfv[n], acc[m][n], 0, 0, 0);
    __builtin_amdgcn_s_setprio(0);
  }
#undef STAGE

  // D layout (verified m89/m91): col = lane&15, row = (lane>>4)*4 + e
  if constexpr (EPI == 2) {
    __syncthreads();                 // all waves done with pool -> ctile
    short (*ctile)[CTS] = (short(*)[CTS])pool;
    #pragma unroll
    for (int m = 0; m < 4; ++m) {
      const int rl0 = wM * 64 + m * 16 + g * 4;
      #pragma unroll
      for (int n = 0; n < FN; ++n) {
        const int cl = wN * (BN / 2) + n * 16 + r;
        const float bv = bias[bn + cl];
        #pragma unroll
        for (int e = 0; e < 4; ++e)
          ctile[rl0 + e][cl] = f2bf(acc[m][n][e] + bv);
      }
    }
    __syncthreads();
    #pragma unroll
    for (int it = 0; it < (128 * BN / 8) / 256; ++it) {
      int id = it * 256 + tid;
      int rowL = id / (BN / 8), c8 = id % (BN / 8);
      *(short8*)&Cb[(size_t)(bm + rowL) * N + bn + c8 * 8] =
          *(short8*)&ctile[rowL][c8 * 8];
    }
  } else if constexpr (EPI == 1) {
    __syncthreads();
    short (*ctile)[CTS] = (short(*)[CTS])pool;
    #pragma unroll
    for (int m = 0; m < 4; ++m) {
      const int rl0 = wM * 64 + m * 16 + g * 4;
      const int row0 = bm + rl0;
      #pragma unroll
      for (int n = 0; n < FN; ++n) {
        const int colbase = bn + wN * (BN / 2) + n * 16;
        if (colbase < 2048) {
          const int cl = wN * (BN / 2) + n * 16 + r;
          const float bv = bias[colbase + r];
          #pragma unroll
          for (int e = 0; e < 4; ++e) {
            float v = acc[m][n][e] + bv;
            v = (v > 15.f) ? v : log1pf(__expf(v));
            ctile[rl0 + e][cl] = f2bf(v);
          }
        } else if (colbase == 2048) {
          const float bv = bx[NDS + r];
          #pragma unroll
          for (int e = 0; e < 4; ++e)
            Bm[(size_t)(row0 + e) * NDS + r] = acc[m][n][e] + bv;
        }
      }
    }
    __syncthreads();
    if (bn < 2048) {
      // drain 128xBN ctile into FG (rr-minor -> contiguous 16B chunks)
      constexpr int CH = 2 * BN;          // units per 16-row group
      #pragma unroll
      for (int it = 0; it < (8 * CH) / 256; ++it) {
        int unit = it * 256 + tid;
        int grp = unit / CH, wi = unit % CH;
        int k8l = wi >> 4, rr = wi & 15;
        *(short8*)&Cb[(size_t)((bm >> 4) + grp) * (NDI * 16) +
                      (size_t)((bn >> 3) + k8l) * 128 + rr * 8] =
            *(short8*)&ctile[grp * 16 + rr][k8l * 8];
      }
    }
  } else {
    #pragma unroll
    for (int m = 0; m < 4; ++m) {
      const int row0 = bm + wM * 64 + m * 16 + g * 4;
      #pragma unroll
      for (int n = 0; n < FN; ++n) {
        const int col = bn + wN * (BN / 2) + n * 16 + r;
        const float bv = bias[col];
        #pragma unroll
        for (int e = 0; e < 4; ++e)
          C[(size_t)(row0 + e) * N + col] = acc[m][n][e] + bv;
      }
    }
  }
}

// ---------------------------------------------------------------------------
// depthwise causal conv (width 4) + bias + SiLU; reads bf16 xz;
// writes ONLY xhbf (FG bf16) via slab.
__global__ __launch_bounds__(256) void conv_silu_kernel(
    const short* __restrict__ xz, const float* __restrict__ cw,
    const float* __restrict__ cb, short* __restrict__ xhbf) {
  __shared__ short slab[16][528];
  const int tid = threadIdx.x;
  const int c0 = blockIdx.x * 512;
  const int r0 = blockIdx.y * 16;
  const int b  = r0 >> 11;
  const int t0 = r0 & (NL - 1);
  const short* zbase = xz + ((size_t)b * NL) * (2 * NDI);

  #pragma unroll
  for (int u = 0; u < 4; ++u) {
    int unit = u * 256 + tid;
    int rr = unit >> 6, cc = unit & 63;
    int t = t0 + rr, c = c0 + cc * 8;
    float acc[8];
    #pragma unroll
    for (int e = 0; e < 8; ++e) acc[e] = cb[c + e];
    #pragma unroll
    for (int k = 0; k < NDC; ++k) {
      int tt = t - (NDC - 1) + k;
      if (tt >= 0) {
        short8 rv = *(const short8*)(zbase + (size_t)tt * (2 * NDI) + c);
        #pragma unroll
        for (int e = 0; e < 8; ++e)
          acc[e] += cw[(c + e) * NDC + k] * bf2f(rv[e]);
      }
    }
    #pragma unroll
    for (int e = 0; e < 8; ++e) {
      float s = acc[e] / (1.f + __expf(-acc[e]));
      slab[rr][cc * 8 + e] = f2bf(s);
    }
  }
  __syncthreads();
  short* op = xhbf + (size_t)(r0 >> 4) * NDI * 16 + (size_t)(c0 >> 3) * 128;
  #pragma unroll
  for (int u = 0; u < 4; ++u) {
    int u2 = u * 256 + tid;
    int rr = u2 & 15, q = u2 >> 4;
    *(short8*)&op[q * 128 + rr * 8] = *(short8*)&slab[rr][q * 8];
  }
}

// ---------------------------------------------------------------------------
// scan scratch layout: [b][k][c][s]
__device__ __forceinline__ size_t scoff(int b, int k, int c) {
  return (((size_t)b * CCH + k) * NDI + c) * NDS;
}

// phase 1: thread = (b, c, chunk); 16 states in registers; u,d from FG bf16.
__global__ __launch_bounds__(256) void scan_p1_kernel(
    const short* __restrict__ dbf, const float* __restrict__ Bm,
    const short* __restrict__ xhbf, const float* __restrict__ A_log,
    float* __restrict__ Pbuf, float* __restrict__ Hend) {
  const int i = blockIdx.x * 256 + threadIdx.x;
  const int c = i & (NDI - 1);
  const int k = (i >> 11) & (CCH - 1);
  const int b = i >> 16;
  const int t0 = k * CLEN;

  float Av[NDS];
  #pragma unroll
  for (int s = 0; s < NDS; ++s) Av[s] = -__expf(A_log[c * NDS + s]);

  const size_t fgb = (size_t)((b * NL + t0) >> 4) * (NDI * 16) +
                     (size_t)(c >> 3) * 128 + (c & 7);
  const short* up = xhbf + fgb;
  const short* dp = dbf + fgb;
  const f32x4* Bp = (const f32x4*)(Bm + ((size_t)(b * NL + t0)) * NDS);

  float h[NDS], P[NDS];
  #pragma unroll
  for (int s = 0; s < NDS; ++s) { h[s] = 0.f; P[s] = 1.f; }

  #pragma unroll 4
  for (int j = 0; j < CLEN; ++j) {
    const size_t o = (size_t)(j >> 4) * (NDI * 16) + (j & 15) * 8;
    const float d = bf2f(dp[o]);
    const float u = bf2f(up[o]);
    f32x4 B0 = Bp[j * 4 + 0], B1 = Bp[j * 4 + 1];
    f32x4 B2 = Bp[j * 4 + 2], B3 = Bp[j * 4 + 3];
    const float du = d * u;
    float Bv[NDS];
    #pragma unroll
    for (int e = 0; e < 4; ++e) {
      Bv[e] = B0[e]; Bv[4 + e] = B1[e]; Bv[8 + e] = B2[e]; Bv[12 + e] = B3[e];
    }
    #pragma unroll
    for (int s = 0; s < NDS; ++s) {
      float dA = __expf(d * Av[s]);
      h[s] = dA * h[s] + du * Bv[s];
      P[s] *= dA;
    }
  }

  const size_t base = scoff(b, k, c);
  #pragma unroll
  for (int q = 0; q < 4; ++q) {
    *(f32x4*)&Pbuf[base + q * 4] = (f32x4){P[q*4], P[q*4+1], P[q*4+2], P[q*4+3]};
    *(f32x4*)&Hend[base + q * 4] = (f32x4){h[q*4], h[q*4+1], h[q*4+2], h[q*4+3]};
  }
}

// ---------------------------------------------------------------------------
// phase 2: thread = (b, c, s); serial combine across the chunks.
__global__ __launch_bounds__(256) void scan_p2_kernel(
    const float* __restrict__ Pbuf, const float* __restrict__ Hend,
    float* __restrict__ Hin) {
  const int i = blockIdx.x * 256 + threadIdx.x;
  const int s = i & (NDS - 1);
  const int c = (i >> 4) & (NDI - 1);
  const int b = i >> 15;
  const size_t step = (size_t)NDI * NDS;
  const size_t base = scoff(b, 0, c) + s;
  float h = 0.f;
  #pragma unroll 8
  for (int k = 0; k < CCH; ++k) {
    Hin[base + (size_t)k * step] = h;
    h = Hend[base + (size_t)k * step] + Pbuf[base + (size_t)k * step] * h;
  }
}

// ---------------------------------------------------------------------------
// phase 3 + merge: rescan; y = (sum_s h + u*D) * silu(z); u,delta from FG
// bf16; z from bf16 xz; LDS slab-transpose -> FG bf16 output.
__global__ __launch_bounds__(256) void scan_p3_kernel(
    const short* __restrict__ dbf, const float* __restrict__ Bm,
    const short* __restrict__ xhbf, const float* __restrict__ A_log,
    const float* __restrict__ Hin, const float* __restrict__ Dvec,
    const short* __restrict__ xz, short* __restrict__ ybf) {
  const int tid = threadIdx.x;
  const int i = blockIdx.x * 256 + tid;
  const int c = i & (NDI - 1);
  const int k = (i >> 11) & (CCH - 1);
  const int b = i >> 16;
  const int t0 = k * CLEN;
  const int cb0 = (blockIdx.x * 256) & (NDI - 1);

  __shared__ float ylds[16][257];

  float Av[NDS];
  #pragma unroll
  for (int s = 0; s < NDS; ++s) Av[s] = -__expf(A_log[c * NDS + s]);
  const float dcoef = Dvec[c];

  const size_t fgb = (size_t)((b * NL + t0) >> 4) * (NDI * 16) +
                     (size_t)(c >> 3) * 128 + (c & 7);
  const short* up = xhbf + fgb;
  const short* dp = dbf + fgb;
  const f32x4* Bp = (const f32x4*)(Bm + ((size_t)(b * NL + t0)) * NDS);
  const short* zp = xz + ((size_t)(b * NL + t0)) * (2 * NDI) + NDI + c;

  const size_t base = scoff(b, k, c);
  float h[NDS];
  #pragma unroll
  for (int s = 0; s < NDS; ++s) h[s] = Hin[base + s];

  for (int j = 0; j < CLEN; ++j) {
    const size_t o = (size_t)(j >> 4) * (NDI * 16) + (j & 15) * 8;
    const float d = bf2f(dp[o]);
    const float u = bf2f(up[o]);
    f32x4 B0 = Bp[j * 4 + 0], B1 = Bp[j * 4 + 1];
    f32x4 B2 = Bp[j * 4 + 2], B3 = Bp[j * 4 + 3];
    const float du = d * u;
    float Bv[NDS];
    #pragma unroll
    for (int e = 0; e < 4; ++e) {
      Bv[e] = B0[e]; Bv[4 + e] = B1[e]; Bv[8 + e] = B2[e]; Bv[12 + e] = B3[e];
    }
    #pragma unroll
    for (int s = 0; s < NDS; ++s) {
      float dA = __expf(d * Av[s]);
      h[s] = dA * h[s] + du * Bv[s];
    }
    float sum01 = 0.f, sum23 = 0.f;
    #pragma unroll
    for (int s = 0; s < 8; ++s)  sum01 += h[s];
    #pragma unroll
    for (int s = 8; s < 16; ++s) sum23 += h[s];
    float y = sum01 + sum23 + u * dcoef;
    float z = bf2f(zp[(size_t)j * (2 * NDI)]);
    y *= z / (1.f + __expf(-z));
    ylds[j & 15][tid] = y;

    if ((j & 15) == 15) {
      __syncthreads();
      const int jb = j - 15;
      #pragma unroll
      for (int s2 = 0; s2 < 2; ++s2) {
        int u2 = tid + 256 * s2;
        int tt = u2 & 15, q = u2 >> 4;
        short8 v;
        #pragma unroll
        for (int e = 0; e < 8; ++e) v[e] = f2bf(ylds[tt][q * 8 + e]);
        int grow = b * NL + t0 + jb + tt;
        int k8 = (cb0 >> 3) + q;
        *(short8*)&ybf[fgoff(grow, k8, NDI)] = v;
      }
      __syncthreads();
    }
  }
}

// ---------------------------------------------------------------------------
extern "C" void kernel_launch(void* const* d_in, const int* in_sizes, int n_in,
                              void* d_out, int out_size, void* d_ws, size_t ws_size,
                              hipStream_t stream) {
  const float* x      = (const float*)d_in[0];
  const float* W_in   = (const float*)d_in[1];
  const float* b_in   = (const float*)d_in[2];
  const float* conv_w = (const float*)d_in[3];
  const float* conv_b = (const float*)d_in[4];
  const float* W_x    = (const float*)d_in[5];
  const float* b_x    = (const float*)d_in[6];
  const float* W_dt   = (const float*)d_in[7];
  const float* b_dt   = (const float*)d_in[8];
  const float* A_log  = (const float*)d_in[9];
  const float* Dv     = (const float*)d_in[10];
  const float* W_out  = (const float*)d_in[11];
  const float* b_out  = (const float*)d_in[12];
  float* out = (float*)d_out;

  char* w = (char*)d_ws;
  short* xbf   = (short*)(w);                  // FG 4096x1024 bf16   8.39MB
  short* WtIn  = (short*)(w + 8388608);        // FG 4096x1024 bf16   8.39MB
  short* WtCat = (short*)(w + 16777216);       // FG 2176x2048 bf16   8.91MB
  short* WtOut = (short*)(w + 25690112);       // FG 1024x2048 bf16   4.19MB
  short* xzbf  = (short*)(w + 29884416);       // 4096x4096 bf16     33.55MB
  short* xhbf  = (short*)(w + 96993280);       // FG 4096x2048 bf16  16.78MB
  short* dbf   = (short*)(w + 113770496);      // FG 4096x2048 bf16  16.78MB
  float* Bm    = (float*)(w + 147324928);      // 4096x16   f32       0.26MB
  short* ybf   = (short*)(w + 147587072);      // FG 4096x2048 bf16  16.78MB
  // scan scratch aliases buffers dead by scan time (8.39MB each):
  float* Pbuf  = (float*)(w);                  // aliases xbf
  float* Hend  = (float*)(w + 8388608);        // aliases WtIn
  float* Hin   = (float*)(w + 16777216);       // aliases WtCat head

  // 0) zero Wcat pad groups 129..135 (rows 2064..2175) once per call
  hipMemsetAsync((char*)WtCat + (size_t)129 * 65536, 0, 7 * 65536, stream);

  // 1) converts / weight transposes into FG layout
  cvt_fg_kernel<<<MROWS / 16, 256, 0, stream>>>(x, xbf);
  transpose_fg_kernel<<<dim3((2 * NDI) / 32, NDM / 64), dim3(32, 8), 0, stream>>>(
      W_in, WtIn, NDM, 2 * NDI);
  transpose_fg_kernel<<<dim3(NDI / 32, NDI / 64), dim3(32, 8), 0, stream>>>(
      W_dt, WtCat, NDI, NDI);
  wx_fg_kernel<<<16, 256, 0, stream>>>(W_x, WtCat);
  transpose_fg_kernel<<<dim3(NDM / 32, NDI / 64), dim3(32, 8), 0, stream>>>(
      W_out, WtOut, NDI, NDM);

  // 2) xz = x @ W_in + b_in -> bf16 row-major (EPI=2, K=1024; 1024 blocks)
  gemm_fg_kernel<128, 2, 1024><<<dim3((2 * NDI) / 128, MROWS / 128), 256, 0, stream>>>(
      xbf, WtIn, b_in, nullptr, xzbf, nullptr, nullptr, MROWS, 2 * NDI);

  // 3) depthwise conv + silu (reads bf16 xz; writes xhbf FG only)
  conv_silu_kernel<<<dim3(NDI / 512, MROWS / 16), 256, 0, stream>>>(
      xzbf, conv_w, conv_b, xhbf);

  // 4+5) fused: [delta(bf16 FG) | Bmat] = xh @ [W_dt | W_x[:,16:32]]
  //      (EPI=1, K=2048; 17x32 = 544 blocks)
  gemm_fg_kernel<128, 1, 2048><<<dim3(2176 / 128, MROWS / 128), 256, 0, stream>>>(
      xhbf, WtCat, b_dt, nullptr, dbf, Bm, b_x, MROWS, NDI);

  // 6) selective scan (chunked: local scan -> chunk combine -> rescan+merge)
  scan_p1_kernel<<<(NB * NDI * CCH) / 256, 256, 0, stream>>>(
      dbf, Bm, xhbf, A_log, Pbuf, Hend);
  scan_p2_kernel<<<(NB * NDI * NDS) / 256, 256, 0, stream>>>(Pbuf, Hend, Hin);
  scan_p3_kernel<<<(NB * NDI * CCH) / 256, 256, 0, stream>>>(
      dbf, Bm, xhbf, A_log, Hin, Dv, xzbf, ybf);

  // 7) out = y @ W_out + b_out  (EPI=0, BN=64, K=2048; 16x32 = 512 blocks)
  gemm_fg_kernel<64, 0, 2048><<<dim3(NDM / 64, MROWS / 128), 256, 0, stream>>>(
      ybf, WtOut, b_out, out, nullptr, nullptr, nullptr, MROWS, NDM);
}